// Round 7
// baseline (102.212 us; speedup 1.0000x reference)
//
#include <hip/hip_runtime.h>

#define TWO_PI 6.28318530717958647692f
// XOR-swizzle for float2 LDS array of 4096: nibble0 ^= nibble1.
#define SWZ(i) ((i) ^ (((i) >> 4) & 15))

// ---- elementwise float2 helpers ----
__device__ __forceinline__ float2 vadd(float2 a, float2 b) { return make_float2(a.x + b.x, a.y + b.y); }
__device__ __forceinline__ float2 vsub(float2 a, float2 b) { return make_float2(a.x - b.x, a.y - b.y); }
__device__ __forceinline__ float2 iperp(float2 z) { return make_float2(-z.y, z.x); }   // i*z

// a*b = b.x*a + b.y*(i*a)
__device__ __forceinline__ float2 cmul(float2 a, float2 b) {
    float2 p = iperp(a);
    return make_float2(fmaf(b.y, p.x, b.x * a.x), fmaf(b.y, p.y, b.x * a.y));
}

// z * (wr + i*S*wi), S compile-time sign
template<int SIGN>
__device__ __forceinline__ float2 twm(float2 z, float wr, float wi) {
    float2 p = iperp(z);
    const float swi = (SIGN > 0) ? wi : -wi;
    return make_float2(fmaf(swi, p.x, wr * z.x), fmaf(swi, p.y, wr * z.y));
}

// e^{S*i*th} for th in [0, 0.37]: Taylor, err < 2e-7 on this range.
__device__ __forceinline__ float2 eiw(float th, float S) {
    float t2 = th * th;
    float sn = th * (1.0f + t2 * (-1.0f / 6.0f + t2 * (1.0f / 120.0f)));
    float cs = 1.0f + t2 * (-0.5f + t2 * (1.0f / 24.0f + t2 * (-1.0f / 720.0f)));
    return make_float2(cs, S * sn);
}

// Multiply v[1..15] by w^idx using 4a+b factorization: w^{4a+b} = (w^4)^a * w^b.
// Depth ~6 instead of a 15-long serial cmul chain.
__device__ __forceinline__ void twiddle_pows(float2* v, float2 w) {
    float2 w2 = cmul(w, w);
    float2 w3 = cmul(w2, w);
    float2 w4 = cmul(w2, w2);
    float2 A1 = w4;
    float2 A2 = cmul(w4, w4);
    float2 A3 = cmul(A2, w4);
    // b-part
    #pragma unroll
    for (int a = 0; a < 4; ++a) {
        v[a * 4 + 1] = cmul(v[a * 4 + 1], w);
        v[a * 4 + 2] = cmul(v[a * 4 + 2], w2);
        v[a * 4 + 3] = cmul(v[a * 4 + 3], w3);
    }
    // a-part
    #pragma unroll
    for (int b = 0; b < 4; ++b) {
        v[4 + b]  = cmul(v[4 + b],  A1);
        v[8 + b]  = cmul(v[8 + b],  A2);
        v[12 + b] = cmul(v[12 + b], A3);
    }
}

// Same but with an extra base factor folded into the a-part: v[4a+b] *= base*w^{4a+b}.
__device__ __forceinline__ void twiddle_pows_base(float2* v, float2 w, float2 base) {
    float2 w2 = cmul(w, w);
    float2 w3 = cmul(w2, w);
    float2 w4 = cmul(w2, w2);
    float2 A0 = base;
    float2 A1 = cmul(base, w4);
    float2 A2 = cmul(A1, w4);
    float2 A3 = cmul(A2, w4);
    #pragma unroll
    for (int a = 0; a < 4; ++a) {
        v[a * 4 + 1] = cmul(v[a * 4 + 1], w);
        v[a * 4 + 2] = cmul(v[a * 4 + 2], w2);
        v[a * 4 + 3] = cmul(v[a * 4 + 3], w3);
    }
    #pragma unroll
    for (int b = 0; b < 4; ++b) {
        v[b]      = cmul(v[b],      A0);
        v[4 + b]  = cmul(v[4 + b],  A1);
        v[8 + b]  = cmul(v[8 + b],  A2);
        v[12 + b] = cmul(v[12 + b], A3);
    }
}

// 4-pt butterfly core
template<int SIGN>
__device__ __forceinline__ void bf4core(float2 a, float2 b, float2 c, float2 d,
                                        float2& ac, float2& as, float2& bd, float2& ib) {
    ac = vadd(a, c); as = vsub(a, c);
    bd = vadd(b, d);
    float2 bs = vsub(b, d);
    ib = (SIGN > 0) ? make_float2(-bs.y, bs.x) : make_float2(bs.y, -bs.x);
}

// 16-point DFT, in-place. OUTSEL: 0 = all; 1 = only v[4..11]; 2 = only v[0..7].
template<int SIGN, int OUTSEL>
__device__ __forceinline__ void fft16(float2* v) {
    float2 t[16];
    #pragma unroll
    for (int k1 = 0; k1 < 4; ++k1) {
        float2 ac, as, bd, ib;
        bf4core<SIGN>(v[k1], v[k1 + 4], v[k1 + 8], v[k1 + 12], ac, as, bd, ib);
        t[k1 * 4 + 0] = vadd(ac, bd);
        t[k1 * 4 + 1] = vadd(as, ib);
        t[k1 * 4 + 2] = vsub(ac, bd);
        t[k1 * 4 + 3] = vsub(as, ib);
    }
    const float c1 = 0.92387953251128674f;     // cos(pi/8)
    const float s1 = 0.38268343236508977f;     // sin(pi/8)
    const float c2 = 0.70710678118654752f;     // cos(pi/4)
    t[5]  = twm<SIGN>(t[5],  c1,  s1);
    t[6]  = twm<SIGN>(t[6],  c2,  c2);
    t[7]  = twm<SIGN>(t[7],  s1,  c1);
    t[9]  = twm<SIGN>(t[9],  c2,  c2);
    t[10] = twm<SIGN>(t[10], 0.f, 1.f);
    t[11] = twm<SIGN>(t[11], -c2, c2);
    t[13] = twm<SIGN>(t[13], s1,  c1);
    t[14] = twm<SIGN>(t[14], -c2, c2);
    t[15] = twm<SIGN>(t[15], -c1, -s1);
    #pragma unroll
    for (int n2 = 0; n2 < 4; ++n2) {
        float2 ac, as, bd, ib;
        bf4core<SIGN>(t[n2], t[4 + n2], t[8 + n2], t[12 + n2], ac, as, bd, ib);
        if (OUTSEL != 1) v[n2 + 0]  = vadd(ac, bd);
        v[n2 + 4]  = vadd(as, ib);
        if (OUTSEL != 2) v[n2 + 8]  = vsub(ac, bd);
        if (OUTSEL == 0) v[n2 + 12] = vsub(as, ib);
    }
}

// 4096-pt DFT, 256 threads, radix-16 x3, swizzled float2 LDS (32768 B), TWO barriers.
// k = k1 + 16*k2 + 256*k3 ; n = n3 + 16*n2 + 256*n1.
// Step-2 writes back into the SAME slots it read (per-thread private set) -> no
// barrier between step-2 read and write. Step-3 reads the remapped layout.
template<int SIGN, int OUTSEL>
__device__ __forceinline__ void fft4096(float2* v, float2* s, int t) {
    const float S = (float)SIGN;
    // ---- step 1: DFT over k3 -> n3 ; twiddle W256^{SIGN*n3*k2}
    {
        const int k1 = t & 15, k2 = t >> 4;
        fft16<SIGN, 0>(v);
        float2 w = eiw(TWO_PI * (float)k2 * (1.0f / 256.0f), S);
        twiddle_pows(v, w);
        #pragma unroll
        for (int n3 = 0; n3 < 16; ++n3)
            s[SWZ(k2 * 256 + k1 * 16 + n3)] = v[n3];
    }
    __syncthreads();
    // ---- step 2: DFT over k2 -> n2 ; twiddle W4096^{SIGN*(n3+16*n2)*k1}
    {
        const int n3 = t & 15, k1 = t >> 4;
        #pragma unroll
        for (int k2 = 0; k2 < 16; ++k2)
            v[k2] = s[SWZ(k2 * 256 + k1 * 16 + n3)];
        fft16<SIGN, 0>(v);
        float2 base = eiw(TWO_PI * (float)(n3 * k1) * (1.0f / 4096.0f), S);
        float2 wst  = eiw(TWO_PI * (float)k1 * (1.0f / 256.0f), S);
        twiddle_pows_base(v, wst, base);
        // write back into the SAME slots read above (k2-slot n2): no barrier needed
        #pragma unroll
        for (int n2 = 0; n2 < 16; ++n2)
            s[SWZ(n2 * 256 + k1 * 16 + n3)] = v[n2];
    }
    __syncthreads();
    // ---- step 3: DFT over k1 -> n1 ; thread t = n3 + 16*n2
    {
        const int n3 = t & 15, n2 = t >> 4;
        #pragma unroll
        for (int k1 = 0; k1 < 16; ++k1)
            v[k1] = s[SWZ(n2 * 256 + k1 * 16 + n3)];
        fft16<SIGN, OUTSEL>(v);
    }
}

// Stage 1: forward FFT of reflect-padded x. xh[b*2048 + k], k in [0,2048).
__global__ __launch_bounds__(256) void kfwd(const float* __restrict__ x,
                                            float2* __restrict__ xh) {
    __shared__ float2 sbuf[4096];
    const int t = threadIdx.x, b = blockIdx.x;
    const float* xr = x + b * 2048;
    float2 v[16];
    #pragma unroll
    for (int k3 = 0; k3 < 16; ++k3) {
        int j = t + 256 * k3 - 1024;           // reflect pad
        j = (j < 0) ? -j : ((j >= 2048) ? (4094 - j) : j);
        j &= 2047;
        v[k3] = make_float2(xr[j], 0.0f);
    }
    fft4096<-1, 2>(v, sbuf, t);
    float2* xo = xh + b * 2048;
    #pragma unroll
    for (int n1 = 0; n1 < 8; ++n1)
        xo[t + 256 * n1] = v[n1];
}

// Stage 2 (packed pairs): Hermitian-symmetrize scales a0=2p, a1=2p+1; pack
// Z = Za + i*Zb; one complex iFFT -> row a0 in .x, a1 in .y. Crop n1 in [4,12).
__global__ __launch_bounds__(256) void kinv2(const float* __restrict__ Psih,
                                             const float2* __restrict__ xh,
                                             float* __restrict__ out,
                                             long long out_cap) {
    __shared__ float2 sbuf[4096];
    const int t = threadIdx.x;
    const int blk = blockIdx.x;                // 4096 = 32 b * 128 pairs
    const int ap = blk & 127, b = blk >> 7;
    const int a0 = ap * 2;
    const float* pa = Psih + (size_t)a0 * 4096;
    const float* pb = pa + 4096;
    const float2* xr = xh + (size_t)b * 2048;
    const float s = 0.5f / 4096.0f;            // Hermitian 1/2 * ifft 1/N
    float2 v[16];
    #pragma unroll
    for (int k3 = 0; k3 < 8; ++k3) {           // k in [0,2048): Z = s*X*(Pa+iPb)
        int k = t + 256 * k3;
        float px = pa[k] * s, py = pb[k] * s;
        float2 X = xr[k];
        v[k3] = make_float2(px * X.x - py * X.y, py * X.x + px * X.y);
    }
    #pragma unroll
    for (int k3 = 8; k3 < 16; ++k3) {          // k in [2048,4096): Z = s*conj(X[m])*(Pa[m]+iPb[m])
        int m = 4096 - (t + 256 * k3);         // m in [1,2048]
        float px = pa[m] * s, py = pb[m] * s;  // P[2048]==0
        float2 X = xr[m & 2047];               // mask no-op except m==2048 (P==0)
        v[k3] = make_float2(px * X.x + py * X.y, py * X.x - px * X.y);
    }
    fft4096<1, 1>(v, sbuf, t);
    const long long base = ((long long)b * 256 + a0) * 2048;
    #pragma unroll
    for (int n1 = 4; n1 < 12; ++n1) {          // n = t + 256*n1, crop [1024,3072)
        long long oi = base + t + 256 * (n1 - 4);
        if (oi < out_cap) out[oi] = v[n1].x;             // row a0
        long long oj = oi + 2048;
        if (oj < out_cap) out[oj] = v[n1].y;             // row a1
    }
}

// Fallback if workspace unusable: fused fwd+mul+inv, packed pairs.
__global__ __launch_bounds__(256) void kfused2(const float* __restrict__ x,
                                               const float* __restrict__ Psih,
                                               float* __restrict__ out,
                                               long long out_cap) {
    __shared__ float2 sbuf[4096];
    const int t = threadIdx.x;
    const int blk = blockIdx.x;
    const int ap = blk & 127, b = blk >> 7;
    const int a0 = ap * 2;
    const float* xr = x + b * 2048;
    float2 v[16];
    #pragma unroll
    for (int k3 = 0; k3 < 16; ++k3) {
        int j = t + 256 * k3 - 1024;
        j = (j < 0) ? -j : ((j >= 2048) ? (4094 - j) : j);
        j &= 2047;
        v[k3] = make_float2(xr[j], 0.0f);
    }
    fft4096<-1, 0>(v, sbuf, t);
    const float* pa = Psih + (size_t)a0 * 4096;
    const float* pb = pa + 4096;
    const float s = 0.5f / 4096.0f;
    #pragma unroll
    for (int n1 = 0; n1 < 16; ++n1) {
        int k = t + 256 * n1;
        int idx = (k < 2048) ? k : (4096 - k);
        float px = pa[idx] * s, py = pb[idx] * s;
        float2 X = v[n1];
        v[n1] = make_float2(px * X.x - py * X.y, py * X.x + px * X.y);
    }
    __syncthreads();
    fft4096<1, 1>(v, sbuf, t);
    const long long base = ((long long)b * 256 + a0) * 2048;
    #pragma unroll
    for (int n1 = 4; n1 < 12; ++n1) {
        long long oi = base + t + 256 * (n1 - 4);
        if (oi < out_cap) out[oi] = v[n1].x;
        long long oj = oi + 2048;
        if (oj < out_cap) out[oj] = v[n1].y;
    }
}

extern "C" void kernel_launch(void* const* d_in, const int* in_sizes, int n_in,
                              void* d_out, int out_size, void* d_ws, size_t ws_size,
                              hipStream_t stream) {
    const float* x = (const float*)d_in[0];
    const float* Psih = (const float*)d_in[1];
    float* out = (float*)d_out;
    const long long out_cap = (long long)out_size;   // float32 elements
    const size_t xh_bytes = (size_t)32 * 2048 * sizeof(float2);   // 512 KB
    if (ws_size >= xh_bytes && d_ws != nullptr) {
        float2* xh = (float2*)d_ws;
        kfwd<<<32, 256, 0, stream>>>(x, xh);
        kinv2<<<4096, 256, 0, stream>>>(Psih, xh, out, out_cap);
    } else {
        kfused2<<<4096, 256, 0, stream>>>(x, Psih, out, out_cap);
    }
}